// Round 1
// 167.412 us; speedup vs baseline: 1.2111x; 1.2111x over previous
//
#include <hip/hip_runtime.h>
#include <math.h>

#define DDIM 4096
#define NSEG 100
#define HDIM 128
#define BROWS 4096
#define TOPK 10

// Branch-free gelu: A&S 7.1.26 erf (abs err <= 1.5e-7), v_exp_f32 + v_rcp_f32.
__device__ __forceinline__ float gelu_f(float x) {
    float u  = x * 0.70710678118654752440f;
    float au = fminf(fabsf(u), 3.9f);                 // erf(3.9) == 1 to fp32
    float t  = __builtin_amdgcn_rcpf(fmaf(0.3275911f, au, 1.0f));
    float p  = fmaf(fmaf(fmaf(fmaf(1.061405429f, t, -1.453152027f), t,
                              1.421413741f), t, -0.284496736f), t, 0.254829592f) * t;
    float e  = __expf(-au * au);
    float er = fmaf(-p, e, 1.0f);                     // erf(|u|)
    er = copysignf(er, u);
    return 0.5f * x * (1.0f + er);
}

// ---------- K1: seg-side GEMM partials: segp[ks][n][col], 64 k-slices of 64 ----------
// grid (25, 64), block 256
__global__ void k_seg_gemm(const float* __restrict__ seg,
                           const float* __restrict__ iw1,
                           const float* __restrict__ rw1,
                           float* __restrict__ segp) {
    __shared__ float segT[64][5];    // [k][n], pad -> 2-way max on write
    int ng = blockIdx.x;
    int ks = blockIdx.y * 64;
    int tid = threadIdx.x;
    {
        int k = tid & 63, j = tid >> 6;
        segT[k][j] = seg[(size_t)(ng * 4 + j) * DDIM + ks + k];
    }
    __syncthreads();

    int col = tid;
    float a0 = 0.f, a1 = 0.f, a2 = 0.f, a3 = 0.f;
    const float* w = (col < HDIM) ? (iw1 + col)
                                  : (rw1 + (size_t)DDIM * HDIM + (col - HDIM));
    #pragma unroll 8
    for (int k = 0; k < 64; ++k) {
        float wv = w[(size_t)(ks + k) * HDIM];
        a0 = fmaf(segT[k][0], wv, a0);
        a1 = fmaf(segT[k][1], wv, a1);
        a2 = fmaf(segT[k][2], wv, a2);
        a3 = fmaf(segT[k][3], wv, a3);
    }
    float* outp = segp + (size_t)blockIdx.y * (NSEG * 256) + (size_t)(ng * 4) * 256 + col;
    outp[0] = a0; outp[256] = a1; outp[512] = a2; outp[768] = a3;
}

// ---------- K2: reduce 64 k-slices -> importance, coeff, shw(+rb1) ----------
// grid 100, block 256
__global__ void k_seg_red(const float* __restrict__ segp,
                          const int* __restrict__ positions,
                          const float* __restrict__ ib1,
                          const float* __restrict__ iw2,
                          const float* __restrict__ ib2,
                          const float* __restrict__ rb1,
                          float* __restrict__ shw, float* __restrict__ impA,
                          float* __restrict__ cA) {
    __shared__ float red[HDIM];
    int n = blockIdx.x, tid = threadIdx.x;
    float v = 0.f;
    #pragma unroll
    for (int s = 0; s < 64; ++s)
        v += segp[(size_t)s * (NSEG * 256) + (size_t)n * 256 + tid];
    if (tid < HDIM) {
        red[tid] = gelu_f(v + ib1[tid]) * iw2[tid];
    } else {
        shw[(size_t)n * HDIM + (tid - HDIM)] = v + rb1[tid - HDIM];
    }
    __syncthreads();
    if (tid == 0) {
        float s = 0.f;
        for (int j = 0; j < HDIM; ++j) s += red[j];
        float imp = 1.f / (1.f + expf(-(s + ib2[0])));
        float pf = powf(0.95f, (float)NSEG - (float)positions[n] - 1.0f);
        impA[n] = imp;
        cA[n] = imp * (0.5f + 0.5f * pf);
    }
}

// ---------- K3: qh partials, fp32, 64m x 128n tile, 8x4 acc/thread ----------
// grid (64, 8), block 256. 32 chunks of 16 k, register-prefetch pipelined.
__global__ void k_qh(const float* __restrict__ query,
                     const float* __restrict__ rw1,
                     float* __restrict__ qhp) {
    __shared__ float As[16][68];     // [k][m], pad 68 -> 2-way max on transposed write
    __shared__ float Bs[16][HDIM];   // [k][n]
    int tid = threadIdx.x;
    int tx = tid & 31;               // n0 = tx*4
    int ty = tid >> 5;               // m0 = ty*8
    int m0g = blockIdx.x * 64;
    int ksg = blockIdx.y * 512;

    float acc[8][4];
    #pragma unroll
    for (int i = 0; i < 8; ++i)
        #pragma unroll
        for (int j = 0; j < 4; ++j) acc[i][j] = 0.f;

    // A stage map: row ar = tid>>2 (0..63), k-quad ak = (tid&3)*4
    int ar = tid >> 2, ak = (tid & 3) * 4;
    // B stage map: row bk = tid>>4 (0..15), col bn = (tid&15)*8
    int bk = tid >> 4, bn = (tid & 15) * 8;

    const float* aptr = query + (size_t)(m0g + ar) * DDIM + ksg + ak;
    const float* bptr = rw1 + (size_t)(ksg + bk) * HDIM + bn;

    float4 areg = *reinterpret_cast<const float4*>(aptr);
    float4 breg0 = *reinterpret_cast<const float4*>(bptr);
    float4 breg1 = *reinterpret_cast<const float4*>(bptr + 4);

    for (int c = 0; c < 32; ++c) {
        __syncthreads();
        As[ak + 0][ar] = areg.x; As[ak + 1][ar] = areg.y;
        As[ak + 2][ar] = areg.z; As[ak + 3][ar] = areg.w;
        *reinterpret_cast<float4*>(&Bs[bk][bn]) = breg0;
        *reinterpret_cast<float4*>(&Bs[bk][bn + 4]) = breg1;
        __syncthreads();
        if (c < 31) {
            const float* ap = aptr + (c + 1) * 16;
            const float* bp = bptr + (size_t)(c + 1) * 16 * HDIM;
            areg = *reinterpret_cast<const float4*>(ap);
            breg0 = *reinterpret_cast<const float4*>(bp);
            breg1 = *reinterpret_cast<const float4*>(bp + 4);
        }
        #pragma unroll
        for (int kk = 0; kk < 16; ++kk) {
            float4 a0 = *reinterpret_cast<const float4*>(&As[kk][ty * 8]);
            float4 a1 = *reinterpret_cast<const float4*>(&As[kk][ty * 8 + 4]);
            float4 b  = *reinterpret_cast<const float4*>(&Bs[kk][tx * 4]);
            float am[8] = {a0.x, a0.y, a0.z, a0.w, a1.x, a1.y, a1.z, a1.w};
            #pragma unroll
            for (int i = 0; i < 8; ++i) {
                acc[i][0] = fmaf(am[i], b.x, acc[i][0]);
                acc[i][1] = fmaf(am[i], b.y, acc[i][1]);
                acc[i][2] = fmaf(am[i], b.z, acc[i][2]);
                acc[i][3] = fmaf(am[i], b.w, acc[i][3]);
            }
        }
    }
    float* outp = qhp + (size_t)blockIdx.y * (BROWS * HDIM);
    #pragma unroll
    for (int i = 0; i < 8; ++i) {
        int row = m0g + ty * 8 + i;
        float4 o = make_float4(acc[i][0], acc[i][1], acc[i][2], acc[i][3]);
        *reinterpret_cast<float4*>(&outp[(size_t)row * HDIM + tx * 4]) = o;
    }
}

// ---------- K4a: rel scores, lane-local h-reduction ----------
// grid 512, block 256: 8 query-rows per block; thread owns segment n, 4 rows.
__global__ __launch_bounds__(256, 2)
void k_rel(const float* __restrict__ qhp,
           const float* __restrict__ shw,
           const float* __restrict__ rw2,
           const float* __restrict__ rb2,
           const float* __restrict__ impA,
           const float* __restrict__ cA,
           float* __restrict__ scoreA,
           float* __restrict__ wimpA) {
    __shared__ float shs[NSEG][129];   // pad 129 -> bank (n+h)%32, 2-way = free
    __shared__ float qs[8][HDIM];
    int tid = threadIdx.x;
    int b0 = blockIdx.x * 8;

    // reduce 8 split-k slices of qh for this block's 8 rows
    for (int idx = tid; idx < 8 * HDIM; idx += 256) {
        int r = idx >> 7, h = idx & 127;
        float v = 0.f;
        #pragma unroll
        for (int s = 0; s < 8; ++s)
            v += qhp[(size_t)s * (BROWS * HDIM) + (size_t)(b0 + r) * HDIM + h];
        qs[r][h] = v;
    }
    // stage shw (already includes rb1) into padded LDS
    for (int e = tid * 4; e < NSEG * HDIM; e += 1024) {
        float4 v = *reinterpret_cast<const float4*>(shw + e);
        int n = e >> 7, h = e & 127;
        shs[n][h]     = v.x; shs[n][h + 1] = v.y;
        shs[n][h + 2] = v.z; shs[n][h + 3] = v.w;
    }
    __syncthreads();

    int n = tid & 127, g = tid >> 7;
    int nn = (n < NSEG) ? n : (NSEG - 1);   // clamp: lanes 100..127 duplicate, writes masked
    int r0 = g * 4;
    float a0 = 0.f, a1 = 0.f, a2 = 0.f, a3 = 0.f;
    #pragma unroll 2
    for (int h = 0; h < HDIM; ++h) {
        float s = shs[nn][h];
        float w = rw2[h];                   // wave-uniform -> scalar load
        a0 = fmaf(gelu_f(qs[r0 + 0][h] + s), w, a0);
        a1 = fmaf(gelu_f(qs[r0 + 1][h] + s), w, a1);
        a2 = fmaf(gelu_f(qs[r0 + 2][h] + s), w, a2);
        a3 = fmaf(gelu_f(qs[r0 + 3][h] + s), w, a3);
    }
    if (n < NSEG) {
        float rb2f = rb2[0];
        float ca = cA[n], ia = impA[n];
        float r_[4];
        r_[0] = 1.f / (1.f + expf(-(a0 + rb2f)));
        r_[1] = 1.f / (1.f + expf(-(a1 + rb2f)));
        r_[2] = 1.f / (1.f + expf(-(a2 + rb2f)));
        r_[3] = 1.f / (1.f + expf(-(a3 + rb2f)));
        #pragma unroll
        for (int r = 0; r < 4; ++r) {
            size_t o = (size_t)(b0 + r0 + r) * 128 + n;
            scoreA[o] = ca * r_[r];
            wimpA[o]  = ia * r_[r];
        }
    }
}

// ---------- K4b: top-10 + weights + context + out ----------
// grid 4096, block 128: 2 waves, each redundantly does register-only top-k (no LDS, no barrier)
__global__ void k_ctx2(const float* __restrict__ query,
                       const float* __restrict__ seg,
                       const float* __restrict__ scoreA,
                       const float* __restrict__ wimpA,
                       float* __restrict__ out) {
    int b = blockIdx.x, tid = threadIdx.x, lane = tid & 63;
    const float* sr = scoreA + (size_t)b * 128;
    const float* wr = wimpA  + (size_t)b * 128;
    float s1 = sr[lane];
    float w1 = wr[lane];
    int i2 = lane + 64;
    float s2 = (i2 < NSEG) ? sr[i2] : -1e30f;
    float w2 = (i2 < NSEG) ? wr[i2] : 0.f;

    float wv[TOPK]; int idxv[TOPK]; float wsum = 0.f;
    #pragma unroll
    for (int k = 0; k < TOPK; ++k) {
        float s; int i;
        if (s2 > s1) { s = s2; i = i2; } else { s = s1; i = lane; }
        #pragma unroll
        for (int off = 1; off < 64; off <<= 1) {
            float os = __shfl_xor(s, off);
            int oi = __shfl_xor(i, off);
            if (os > s || (os == s && oi < i)) { s = os; i = oi; }
        }
        // all lanes now agree on (s, i); fetch wimp[i] by shuffle
        float wi = __shfl((i < 64) ? w1 : w2, i & 63);
        idxv[k] = i; wv[k] = wi; wsum += wi;
        if (i == lane) s1 = -1e30f;
        if (i == i2)   s2 = -1e30f;
    }
    float denom = wsum + 1e-8f;
    float wn[TOPK]; const float* srow[TOPK];
    #pragma unroll
    for (int k = 0; k < TOPK; ++k) {
        wn[k] = wv[k] / denom;
        srow[k] = seg + (size_t)idxv[k] * DDIM;
    }
    const float* qrow = query + (size_t)b * DDIM;
    float* orow = out + (size_t)b * DDIM;
    #pragma unroll
    for (int c = 0; c < 8; ++c) {
        int d0 = c * 512 + tid * 4;
        float4 q4 = *reinterpret_cast<const float4*>(qrow + d0);
        #pragma unroll
        for (int k = 0; k < TOPK; ++k) {
            float4 s4 = *reinterpret_cast<const float4*>(srow[k] + d0);
            q4.x = fmaf(wn[k], s4.x, q4.x); q4.y = fmaf(wn[k], s4.y, q4.y);
            q4.z = fmaf(wn[k], s4.z, q4.z); q4.w = fmaf(wn[k], s4.w, q4.w);
        }
        *reinterpret_cast<float4*>(orow + d0) = q4;
    }
}

extern "C" void kernel_launch(void* const* d_in, const int* in_sizes, int n_in,
                              void* d_out, int out_size, void* d_ws, size_t ws_size,
                              hipStream_t stream) {
    const float* query = (const float*)d_in[0];
    const float* seg   = (const float*)d_in[1];
    const int*   pos   = (const int*)d_in[2];
    const float* iw1   = (const float*)d_in[3];
    const float* ib1   = (const float*)d_in[4];
    const float* iw2   = (const float*)d_in[5];
    const float* ib2   = (const float*)d_in[6];
    const float* rw1   = (const float*)d_in[7];
    const float* rb1   = (const float*)d_in[8];
    const float* rw2   = (const float*)d_in[9];
    const float* rb2   = (const float*)d_in[10];
    float* out = (float*)d_out;

    char* ws = (char*)d_ws;
    float* qhp  = (float*)(ws);                                   // 8*4096*128*4 = 16.8 MB
    float* segp = (float*)(ws + 17 * 1024 * 1024);                // 64*100*256*4 = 6.55 MB
    float* shw  = (float*)(ws + 24 * 1024 * 1024);                // 100*128*4
    float* impA = (float*)(ws + 24 * 1024 * 1024 + 51200);
    float* cA   = (float*)(ws + 24 * 1024 * 1024 + 51200 + 512);
    // scoreA/wimpA reuse segp's region (segp is dead after k_seg_red; stream-ordered)
    float* scoreA = (float*)(ws + 17 * 1024 * 1024);              // 4096*128*4 = 2 MB
    float* wimpA  = (float*)(ws + 19 * 1024 * 1024);              // 2 MB

    hipLaunchKernelGGL(k_seg_gemm, dim3(25, 64), dim3(256), 0, stream, seg, iw1, rw1, segp);
    hipLaunchKernelGGL(k_seg_red, dim3(NSEG), dim3(256), 0, stream,
                       segp, pos, ib1, iw2, ib2, rb1, shw, impA, cA);
    hipLaunchKernelGGL(k_qh, dim3(64, 8), dim3(256), 0, stream, query, rw1, qhp);
    hipLaunchKernelGGL(k_rel, dim3(BROWS / 8), dim3(256), 0, stream,
                       qhp, shw, rw2, rb2, impA, cA, scoreA, wimpA);
    hipLaunchKernelGGL(k_ctx2, dim3(BROWS), dim3(128), 0, stream,
                       query, seg, scoreA, wimpA, out);
}

// Round 2
// 158.514 us; speedup vs baseline: 1.2790x; 1.0561x over previous
//
#include <hip/hip_runtime.h>
#include <math.h>

#define DDIM 4096
#define NSEG 100
#define HDIM 128
#define BROWS 4096
#define TOPK 10

typedef __attribute__((ext_vector_type(8))) short bf16x8;
typedef __attribute__((ext_vector_type(4))) float f32x4;

// Branch-free gelu: A&S 7.1.26 erf (abs err <= 1.5e-7), v_exp_f32 + v_rcp_f32.
__device__ __forceinline__ float gelu_f(float x) {
    float u  = x * 0.70710678118654752440f;
    float au = fminf(fabsf(u), 3.9f);                 // erf(3.9) == 1 to fp32
    float t  = __builtin_amdgcn_rcpf(fmaf(0.3275911f, au, 1.0f));
    float p  = fmaf(fmaf(fmaf(fmaf(1.061405429f, t, -1.453152027f), t,
                              1.421413741f), t, -0.284496736f), t, 0.254829592f) * t;
    float e  = __expf(-au * au);
    float er = fmaf(-p, e, 1.0f);                     // erf(|u|)
    er = copysignf(er, u);
    return 0.5f * x * (1.0f + er);
}

// Split fp32 -> bf16 hi (truncate) + bf16 lo (exact residual, truncated).
// a ~= hi + lo with |err| ~ 2^-16 relative; omitted lo*lo term same order.
__device__ __forceinline__ void split8(const float4& a, const float4& b,
                                       bf16x8& hi, bf16x8& lo) {
    float v[8] = {a.x, a.y, a.z, a.w, b.x, b.y, b.z, b.w};
    uint hw[4], lw[4];
    #pragma unroll
    for (int j = 0; j < 4; ++j) {
        uint u0 = __float_as_uint(v[2 * j]);
        uint u1 = __float_as_uint(v[2 * j + 1]);
        hw[j] = (u0 >> 16) | (u1 & 0xffff0000u);
        float r0 = v[2 * j]     - __uint_as_float(u0 & 0xffff0000u);
        float r1 = v[2 * j + 1] - __uint_as_float(u1 & 0xffff0000u);
        lw[j] = (__float_as_uint(r0) >> 16) | (__float_as_uint(r1) & 0xffff0000u);
    }
    uint4 h = make_uint4(hw[0], hw[1], hw[2], hw[3]);
    uint4 l = make_uint4(lw[0], lw[1], lw[2], lw[3]);
    hi = __builtin_bit_cast(bf16x8, h);
    lo = __builtin_bit_cast(bf16x8, l);
}

// ---------- K1: seg-side GEMM partials: segp[ks][n][col], 64 k-slices of 64 ----------
// grid (25, 64), block 256
__global__ void k_seg_gemm(const float* __restrict__ seg,
                           const float* __restrict__ iw1,
                           const float* __restrict__ rw1,
                           float* __restrict__ segp) {
    __shared__ float segT[64][5];    // [k][n], pad -> 2-way max on write
    int ng = blockIdx.x;
    int ks = blockIdx.y * 64;
    int tid = threadIdx.x;
    {
        int k = tid & 63, j = tid >> 6;
        segT[k][j] = seg[(size_t)(ng * 4 + j) * DDIM + ks + k];
    }
    __syncthreads();

    int col = tid;
    float a0 = 0.f, a1 = 0.f, a2 = 0.f, a3 = 0.f;
    const float* w = (col < HDIM) ? (iw1 + col)
                                  : (rw1 + (size_t)DDIM * HDIM + (col - HDIM));
    #pragma unroll 8
    for (int k = 0; k < 64; ++k) {
        float wv = w[(size_t)(ks + k) * HDIM];
        a0 = fmaf(segT[k][0], wv, a0);
        a1 = fmaf(segT[k][1], wv, a1);
        a2 = fmaf(segT[k][2], wv, a2);
        a3 = fmaf(segT[k][3], wv, a3);
    }
    float* outp = segp + (size_t)blockIdx.y * (NSEG * 256) + (size_t)(ng * 4) * 256 + col;
    outp[0] = a0; outp[256] = a1; outp[512] = a2; outp[768] = a3;
}

// ---------- K2: reduce 64 k-slices -> importance, coeff, shw(+rb1) ----------
// grid 100, block 256
__global__ void k_seg_red(const float* __restrict__ segp,
                          const int* __restrict__ positions,
                          const float* __restrict__ ib1,
                          const float* __restrict__ iw2,
                          const float* __restrict__ ib2,
                          const float* __restrict__ rb1,
                          float* __restrict__ shw, float* __restrict__ impA,
                          float* __restrict__ cA) {
    __shared__ float red[HDIM];
    int n = blockIdx.x, tid = threadIdx.x;
    float v = 0.f;
    #pragma unroll
    for (int s = 0; s < 64; ++s)
        v += segp[(size_t)s * (NSEG * 256) + (size_t)n * 256 + tid];
    if (tid < HDIM) {
        red[tid] = gelu_f(v + ib1[tid]) * iw2[tid];
    } else {
        shw[(size_t)n * HDIM + (tid - HDIM)] = v + rb1[tid - HDIM];
    }
    __syncthreads();
    if (tid == 0) {
        float s = 0.f;
        for (int j = 0; j < HDIM; ++j) s += red[j];
        float imp = 1.f / (1.f + expf(-(s + ib2[0])));
        float pf = powf(0.95f, (float)NSEG - (float)positions[n] - 1.0f);
        impA[n] = imp;
        cA[n] = imp * (0.5f + 0.5f * pf);
    }
}

// ---------- K_bt: rw1[:D] -> transposed bf16 hi/lo pair Bt[128][4096] ----------
// grid 256 (k-chunks of 16), block 256
__global__ void k_bt(const float* __restrict__ rw1,
                     ushort* __restrict__ bth, ushort* __restrict__ btl) {
    __shared__ float tile[16][129];
    int tid = threadIdx.x;
    int k0 = blockIdx.x * 16;
    #pragma unroll
    for (int i = 0; i < 8; ++i) {
        int e = i * 256 + tid;
        int k = e >> 7, n = e & 127;
        tile[k][n] = rw1[(size_t)(k0 + k) * HDIM + n];
    }
    __syncthreads();
    int n = tid >> 1, kh = (tid & 1) * 8;
    uint hw[4], lw[4];
    #pragma unroll
    for (int j = 0; j < 4; ++j) {
        float x0 = tile[kh + 2 * j][n];
        float x1 = tile[kh + 2 * j + 1][n];
        uint u0 = __float_as_uint(x0), u1 = __float_as_uint(x1);
        hw[j] = (u0 >> 16) | (u1 & 0xffff0000u);
        float r0 = x0 - __uint_as_float(u0 & 0xffff0000u);
        float r1 = x1 - __uint_as_float(u1 & 0xffff0000u);
        lw[j] = (__float_as_uint(r0) >> 16) | (__float_as_uint(r1) & 0xffff0000u);
    }
    size_t o = (size_t)n * DDIM + k0 + kh;
    *reinterpret_cast<uint4*>(bth + o) = make_uint4(hw[0], hw[1], hw[2], hw[3]);
    *reinterpret_cast<uint4*>(btl + o) = make_uint4(lw[0], lw[1], lw[2], lw[3]);
}

// ---------- K3: qh partials via bf16x3 MFMA ----------
// grid (128, 8), block 64 (1 wave). Wave: 32 rows x 128 cols, K-chunk 512.
// No LDS, no barriers. Same qhp[slice][row][col] layout as before (8 slices).
__global__ __launch_bounds__(64)
void k_qh_mfma(const float* __restrict__ query,
               const ushort* __restrict__ bth,
               const ushort* __restrict__ btl,
               float* __restrict__ qhp) {
    int lane = threadIdx.x;
    int m0 = blockIdx.x * 32;
    int ky = blockIdx.y;
    int k0 = ky * 512;
    int cl = lane & 15;        // A row sel within frag / B-col sel / C col
    int rg = lane >> 4;        // k-group 0..3

    f32x4 acc0[8], acc1[8];
    #pragma unroll
    for (int nf = 0; nf < 8; ++nf) {
        acc0[nf] = (f32x4)0.f;
        acc1[nf] = (f32x4)0.f;
    }

    const float*  a0p = query + (size_t)(m0 + cl) * DDIM + k0 + rg * 8;
    const float*  a1p = a0p + (size_t)16 * DDIM;
    const ushort* bhp = bth + (size_t)cl * DDIM + k0 + rg * 8;
    const ushort* blp = btl + (size_t)cl * DDIM + k0 + rg * 8;

    for (int ks = 0; ks < 16; ++ks) {
        float4 qa0 = *reinterpret_cast<const float4*>(a0p + ks * 32);
        float4 qa1 = *reinterpret_cast<const float4*>(a0p + ks * 32 + 4);
        float4 qb0 = *reinterpret_cast<const float4*>(a1p + ks * 32);
        float4 qb1 = *reinterpret_cast<const float4*>(a1p + ks * 32 + 4);
        bf16x8 ah0, al0, ah1, al1;
        split8(qa0, qa1, ah0, al0);
        split8(qb0, qb1, ah1, al1);
        #pragma unroll
        for (int nf = 0; nf < 8; ++nf) {
            bf16x8 bh = *reinterpret_cast<const bf16x8*>(bhp + (size_t)nf * 16 * DDIM + ks * 32);
            bf16x8 bl = *reinterpret_cast<const bf16x8*>(blp + (size_t)nf * 16 * DDIM + ks * 32);
            acc0[nf] = __builtin_amdgcn_mfma_f32_16x16x32_bf16(ah0, bh, acc0[nf], 0, 0, 0);
            acc1[nf] = __builtin_amdgcn_mfma_f32_16x16x32_bf16(ah1, bh, acc1[nf], 0, 0, 0);
            acc0[nf] = __builtin_amdgcn_mfma_f32_16x16x32_bf16(al0, bh, acc0[nf], 0, 0, 0);
            acc1[nf] = __builtin_amdgcn_mfma_f32_16x16x32_bf16(al1, bh, acc1[nf], 0, 0, 0);
            acc0[nf] = __builtin_amdgcn_mfma_f32_16x16x32_bf16(ah0, bl, acc0[nf], 0, 0, 0);
            acc1[nf] = __builtin_amdgcn_mfma_f32_16x16x32_bf16(ah1, bl, acc1[nf], 0, 0, 0);
        }
    }

    // C/D layout (measured m89): col = lane&15, row = (lane>>4)*4 + reg
    float* op = qhp + (size_t)ky * (BROWS * HDIM);
    int rg4 = rg * 4;
    #pragma unroll
    for (int nf = 0; nf < 8; ++nf) {
        int col = nf * 16 + cl;
        #pragma unroll
        for (int r = 0; r < 4; ++r) {
            op[(size_t)(m0 + rg4 + r) * HDIM + col]      = acc0[nf][r];
            op[(size_t)(m0 + 16 + rg4 + r) * HDIM + col] = acc1[nf][r];
        }
    }
}

// ---------- K4a: rel scores, lane-local h-reduction ----------
// grid 512, block 256: 8 query-rows per block; thread owns segment n, 4 rows.
__global__ __launch_bounds__(256, 2)
void k_rel(const float* __restrict__ qhp,
           const float* __restrict__ shw,
           const float* __restrict__ rw2,
           const float* __restrict__ rb2,
           const float* __restrict__ impA,
           const float* __restrict__ cA,
           float* __restrict__ scoreA,
           float* __restrict__ wimpA) {
    __shared__ float shs[NSEG][129];   // pad 129 -> bank (n+h)%32, 2-way = free
    __shared__ float qs[8][HDIM];
    int tid = threadIdx.x;
    int b0 = blockIdx.x * 8;

    // reduce 8 split-k slices of qh for this block's 8 rows
    for (int idx = tid; idx < 8 * HDIM; idx += 256) {
        int r = idx >> 7, h = idx & 127;
        float v = 0.f;
        #pragma unroll
        for (int s = 0; s < 8; ++s)
            v += qhp[(size_t)s * (BROWS * HDIM) + (size_t)(b0 + r) * HDIM + h];
        qs[r][h] = v;
    }
    // stage shw (already includes rb1) into padded LDS
    for (int e = tid * 4; e < NSEG * HDIM; e += 1024) {
        float4 v = *reinterpret_cast<const float4*>(shw + e);
        int n = e >> 7, h = e & 127;
        shs[n][h]     = v.x; shs[n][h + 1] = v.y;
        shs[n][h + 2] = v.z; shs[n][h + 3] = v.w;
    }
    __syncthreads();

    int n = tid & 127, g = tid >> 7;
    int nn = (n < NSEG) ? n : (NSEG - 1);   // clamp: lanes 100..127 duplicate, writes masked
    int r0 = g * 4;
    float a0 = 0.f, a1 = 0.f, a2 = 0.f, a3 = 0.f;
    #pragma unroll 2
    for (int h = 0; h < HDIM; ++h) {
        float s = shs[nn][h];
        float w = rw2[h];                   // wave-uniform -> scalar load
        a0 = fmaf(gelu_f(qs[r0 + 0][h] + s), w, a0);
        a1 = fmaf(gelu_f(qs[r0 + 1][h] + s), w, a1);
        a2 = fmaf(gelu_f(qs[r0 + 2][h] + s), w, a2);
        a3 = fmaf(gelu_f(qs[r0 + 3][h] + s), w, a3);
    }
    if (n < NSEG) {
        float rb2f = rb2[0];
        float ca = cA[n], ia = impA[n];
        float r_[4];
        r_[0] = 1.f / (1.f + expf(-(a0 + rb2f)));
        r_[1] = 1.f / (1.f + expf(-(a1 + rb2f)));
        r_[2] = 1.f / (1.f + expf(-(a2 + rb2f)));
        r_[3] = 1.f / (1.f + expf(-(a3 + rb2f)));
        #pragma unroll
        for (int r = 0; r < 4; ++r) {
            size_t o = (size_t)(b0 + r0 + r) * 128 + n;
            scoreA[o] = ca * r_[r];
            wimpA[o]  = ia * r_[r];
        }
    }
}

// ---------- K4b: top-10 + weights + context + out ----------
// grid 4096, block 128: 2 waves, each redundantly does register-only top-k (no LDS, no barrier)
__global__ void k_ctx2(const float* __restrict__ query,
                       const float* __restrict__ seg,
                       const float* __restrict__ scoreA,
                       const float* __restrict__ wimpA,
                       float* __restrict__ out) {
    int b = blockIdx.x, tid = threadIdx.x, lane = tid & 63;
    const float* sr = scoreA + (size_t)b * 128;
    const float* wr = wimpA  + (size_t)b * 128;
    float s1 = sr[lane];
    float w1 = wr[lane];
    int i2 = lane + 64;
    float s2 = (i2 < NSEG) ? sr[i2] : -1e30f;
    float w2 = (i2 < NSEG) ? wr[i2] : 0.f;

    float wv[TOPK]; int idxv[TOPK]; float wsum = 0.f;
    #pragma unroll
    for (int k = 0; k < TOPK; ++k) {
        float s; int i;
        if (s2 > s1) { s = s2; i = i2; } else { s = s1; i = lane; }
        #pragma unroll
        for (int off = 1; off < 64; off <<= 1) {
            float os = __shfl_xor(s, off);
            int oi = __shfl_xor(i, off);
            if (os > s || (os == s && oi < i)) { s = os; i = oi; }
        }
        // all lanes now agree on (s, i); fetch wimp[i] by shuffle
        float wi = __shfl((i < 64) ? w1 : w2, i & 63);
        idxv[k] = i; wv[k] = wi; wsum += wi;
        if (i == lane) s1 = -1e30f;
        if (i == i2)   s2 = -1e30f;
    }
    float denom = wsum + 1e-8f;
    float wn[TOPK]; const float* srow[TOPK];
    #pragma unroll
    for (int k = 0; k < TOPK; ++k) {
        wn[k] = wv[k] / denom;
        srow[k] = seg + (size_t)idxv[k] * DDIM;
    }
    const float* qrow = query + (size_t)b * DDIM;
    float* orow = out + (size_t)b * DDIM;
    #pragma unroll
    for (int c = 0; c < 8; ++c) {
        int d0 = c * 512 + tid * 4;
        float4 q4 = *reinterpret_cast<const float4*>(qrow + d0);
        #pragma unroll
        for (int k = 0; k < TOPK; ++k) {
            float4 s4 = *reinterpret_cast<const float4*>(srow[k] + d0);
            q4.x = fmaf(wn[k], s4.x, q4.x); q4.y = fmaf(wn[k], s4.y, q4.y);
            q4.z = fmaf(wn[k], s4.z, q4.z); q4.w = fmaf(wn[k], s4.w, q4.w);
        }
        *reinterpret_cast<float4*>(orow + d0) = q4;
    }
}

extern "C" void kernel_launch(void* const* d_in, const int* in_sizes, int n_in,
                              void* d_out, int out_size, void* d_ws, size_t ws_size,
                              hipStream_t stream) {
    const float* query = (const float*)d_in[0];
    const float* seg   = (const float*)d_in[1];
    const int*   pos   = (const int*)d_in[2];
    const float* iw1   = (const float*)d_in[3];
    const float* ib1   = (const float*)d_in[4];
    const float* iw2   = (const float*)d_in[5];
    const float* ib2   = (const float*)d_in[6];
    const float* rw1   = (const float*)d_in[7];
    const float* rb1   = (const float*)d_in[8];
    const float* rw2   = (const float*)d_in[9];
    const float* rb2   = (const float*)d_in[10];
    float* out = (float*)d_out;

    char* ws = (char*)d_ws;
    float* qhp  = (float*)(ws);                                   // 8*4096*128*4 = 16.8 MB
    float* segp = (float*)(ws + 17 * 1024 * 1024);                // 64*100*256*4 = 6.55 MB
    float* shw  = (float*)(ws + 24 * 1024 * 1024);                // 100*128*4
    float* impA = (float*)(ws + 24 * 1024 * 1024 + 51200);
    float* cA   = (float*)(ws + 24 * 1024 * 1024 + 51200 + 512);
    // Bt hi/lo reuse segp region (segp dead after k_seg_red; k_bt launched after it)
    ushort* bth = (ushort*)(ws + 17 * 1024 * 1024);               // 128*4096*2 = 1 MB
    ushort* btl = (ushort*)(ws + 18 * 1024 * 1024);               // 1 MB
    // scoreA/wimpA overwrite Bt region (Bt dead after k_qh_mfma; stream-ordered)
    float* scoreA = (float*)(ws + 17 * 1024 * 1024);              // 4096*128*4 = 2 MB
    float* wimpA  = (float*)(ws + 19 * 1024 * 1024);              // 2 MB

    hipLaunchKernelGGL(k_seg_gemm, dim3(25, 64), dim3(256), 0, stream, seg, iw1, rw1, segp);
    hipLaunchKernelGGL(k_seg_red, dim3(NSEG), dim3(256), 0, stream,
                       segp, pos, ib1, iw2, ib2, rb1, shw, impA, cA);
    hipLaunchKernelGGL(k_bt, dim3(256), dim3(256), 0, stream, rw1, bth, btl);
    hipLaunchKernelGGL(k_qh_mfma, dim3(128, 8), dim3(64), 0, stream, query, bth, btl, qhp);
    hipLaunchKernelGGL(k_rel, dim3(BROWS / 8), dim3(256), 0, stream,
                       qhp, shw, rw2, rb2, impA, cA, scoreA, wimpA);
    hipLaunchKernelGGL(k_ctx2, dim3(BROWS), dim3(128), 0, stream,
                       query, seg, scoreA, wimpA, out);
}